// Round 2
// baseline (755.739 us; speedup 1.0000x reference)
//
#include <hip/hip_runtime.h>

typedef __bf16 bf16x8 __attribute__((ext_vector_type(8)));
typedef __bf16 bf16x4 __attribute__((ext_vector_type(4)));
typedef float floatx4 __attribute__((ext_vector_type(4)));

#define GK 2048
#define GN 2048
#define S_LEN 2048
#define NH 16
#define DH 128

// ---------------------------------------------------------------------------
// GEMM: C[m][n] = sum_k A[m][k] * B[n][k]
// Templated on operand dtypes: AF32/BF32 = operand is fp32 (convert to bf16 in
// staging); CF32 = write fp32 output (else bf16).
// 128x128 tile, BK=32, 256 threads = 4 waves, each wave 64x64 (4x4 MFMA tiles)
// ---------------------------------------------------------------------------
template <int AF32, int BF32, int CF32>
__global__ __launch_bounds__(256) void gemm_bt(const void* __restrict__ Av,
                                               const void* __restrict__ Bv,
                                               void* __restrict__ Cv) {
    __shared__ __align__(16) __bf16 As[128][40];  // +8 pad: 16B rows stay aligned, 2-way banks
    __shared__ __align__(16) __bf16 Bs[128][40];

    const int t = threadIdx.x;
    const int lane = t & 63;
    const int wave = t >> 6;
    const int m0 = blockIdx.y * 128, n0 = blockIdx.x * 128;
    const int wr = (wave >> 1) * 64, wc = (wave & 1) * 64;
    const int fr = lane & 15, fq = lane >> 4;

    floatx4 acc[4][4] = {};

    // bf16-source staging coords: 8 elems (16B) per thread, 2 row-blocks
    const int lr = t >> 2;          // 0..63
    const int lc = (t & 3) * 8;     // 0,8,16,24
    // fp32-source staging coords: 4 elems (16B) per thread, 4 row-passes
    const int lr3 = t >> 3;         // 0..31
    const int lc3 = (t & 7) * 4;    // 0,4,...,28

    for (int k0 = 0; k0 < GK; k0 += 32) {
        if (AF32) {
            const float* Ap = (const float*)Av + (size_t)(m0 + lr3) * GK + k0 + lc3;
            for (int p = 0; p < 4; p++) {
                const float4 v = *(const float4*)(Ap + (size_t)p * 32 * GK);
                bf16x4 h;
                h[0] = (__bf16)v.x; h[1] = (__bf16)v.y;
                h[2] = (__bf16)v.z; h[3] = (__bf16)v.w;
                *(bf16x4*)&As[lr3 + p * 32][lc3] = h;
            }
        } else {
            const __bf16* Ap = (const __bf16*)Av + (size_t)(m0 + lr) * GK + k0 + lc;
            *(uint4*)&As[lr][lc]      = *(const uint4*)(Ap);
            *(uint4*)&As[lr + 64][lc] = *(const uint4*)(Ap + (size_t)64 * GK);
        }
        if (BF32) {
            const float* Bp = (const float*)Bv + (size_t)(n0 + lr3) * GK + k0 + lc3;
            for (int p = 0; p < 4; p++) {
                const float4 v = *(const float4*)(Bp + (size_t)p * 32 * GK);
                bf16x4 h;
                h[0] = (__bf16)v.x; h[1] = (__bf16)v.y;
                h[2] = (__bf16)v.z; h[3] = (__bf16)v.w;
                *(bf16x4*)&Bs[lr3 + p * 32][lc3] = h;
            }
        } else {
            const __bf16* Bp = (const __bf16*)Bv + (size_t)(n0 + lr) * GK + k0 + lc;
            *(uint4*)&Bs[lr][lc]      = *(const uint4*)(Bp);
            *(uint4*)&Bs[lr + 64][lc] = *(const uint4*)(Bp + (size_t)64 * GK);
        }
        __syncthreads();

        bf16x8 af[4], bfg[4];
        for (int i = 0; i < 4; i++) af[i]  = *(const bf16x8*)&As[wr + i * 16 + fr][fq * 8];
        for (int j = 0; j < 4; j++) bfg[j] = *(const bf16x8*)&Bs[wc + j * 16 + fr][fq * 8];
        for (int i = 0; i < 4; i++)
            for (int j = 0; j < 4; j++)
                acc[i][j] = __builtin_amdgcn_mfma_f32_16x16x32_bf16(af[i], bfg[j], acc[i][j], 0, 0, 0);
        __syncthreads();
    }

    // C/D layout: row = fq*4 + r, col = fr  [m89-verified]
    for (int i = 0; i < 4; i++)
        for (int j = 0; j < 4; j++) {
            const int row = m0 + wr + i * 16 + fq * 4;
            const int col = n0 + wc + j * 16 + fr;
            for (int r = 0; r < 4; r++) {
                if (CF32)
                    ((float*)Cv)[(size_t)(row + r) * GN + col] = acc[i][j][r];
                else
                    ((__bf16*)Cv)[(size_t)(row + r) * GN + col] = (__bf16)acc[i][j][r];
            }
        }
}

// ---------------------------------------------------------------------------
// Fused RMSNorm (per head, DH=128, fp32 math) + RoPE. Activations bf16 in ws;
// rope freqs + norm weights are fp32 inputs.
// One wave per (b,s,h) row: lane j holds elems j and j+64 — exactly the RoPE pair.
// out[j]    = f[s,j,0,0]*t[j] + f[s,j,0,1]*t[j+64]
// out[j+64] = f[s,j,1,0]*t[j] + f[s,j,1,1]*t[j+64]
// ---------------------------------------------------------------------------
__global__ __launch_bounds__(256) void rmsrope(__bf16* __restrict__ qb,
                                               __bf16* __restrict__ kb,
                                               const float* __restrict__ rope,
                                               const float* __restrict__ qw,
                                               const float* __restrict__ kw) {
    const int lane = threadIdx.x & 63;
    const int row = blockIdx.x * 4 + (threadIdx.x >> 6);   // (b*S + s)*H + h
    __bf16* p = (blockIdx.y ? kb : qb) + (size_t)row * DH;
    const float* w = blockIdx.y ? kw : qw;
    const int s = (row >> 4) & (S_LEN - 1);

    float t0 = (float)p[lane];
    float t1 = (float)p[lane + 64];
    float ss = t0 * t0 + t1 * t1;
    for (int o = 32; o; o >>= 1) ss += __shfl_xor(ss, o, 64);
    const float inv = rsqrtf(ss * (1.0f / 128.0f) + 1e-6f);
    t0 *= inv * w[lane];
    t1 *= inv * w[lane + 64];

    const float4 f = *(const float4*)(rope + (size_t)s * 256 + lane * 4);  // (S,1,64,2,2)
    p[lane]      = (__bf16)(f.x * t0 + f.y * t1);
    p[lane + 64] = (__bf16)(f.z * t0 + f.w * t1);
}

// ---------------------------------------------------------------------------
// Flash attention (bf16 in/out via workspace). grid = (S/64, B*H). Block 256 =
// 4 waves; each wave owns 16 Q rows. KV tiles of 32. QK^T and PV via 16x16x32
// MFMA; P round-trips LDS (C/D layout -> A layout); V staged transposed.
// ---------------------------------------------------------------------------
__global__ __launch_bounds__(256) void flash(const __bf16* __restrict__ Q,
                                             const __bf16* __restrict__ K,
                                             const __bf16* __restrict__ V,
                                             __bf16* __restrict__ O) {
    __shared__ __align__(16) __bf16 Ks[32][136];   // [kv][d], pad 8
    __shared__ __align__(16) __bf16 Vt[128][40];   // [d][kv], pad 8
    __shared__ __align__(16) __bf16 Ps[4][16][40]; // per-wave P tile [qr][kv]

    const int t = threadIdx.x;
    const int lane = t & 63, wave = t >> 6;
    const int fr = lane & 15, fq = lane >> 4;
    const int b = blockIdx.y >> 4, h = blockIdx.y & 15;
    const size_t base = (size_t)b * ((size_t)S_LEN * NH * DH) + (size_t)h * DH;
    const int q0 = blockIdx.x * 64 + wave * 16;
    const float sc = 0.08838834764831845f;  // 1/sqrt(128)

    // Preload Q fragments (A layout), 4 K-chunks of 32
    bf16x8 qf[4];
    {
        const __bf16* qp = Q + base + (size_t)(q0 + fr) * (NH * DH) + fq * 8;
        for (int c = 0; c < 4; c++) qf[c] = *(const bf16x8*)(qp + c * 32);
    }

    floatx4 oa[8] = {};
    float m_i[4] = {-1e30f, -1e30f, -1e30f, -1e30f};
    float l_i[4] = {0.f, 0.f, 0.f, 0.f};

    const int srow = t >> 4;          // 0..15
    const int scol = (t & 15) * 8;    // 0..120
    const __bf16* Kp = K + base + (size_t)srow * (NH * DH) + scol;
    const __bf16* Vp = V + base + (size_t)srow * (NH * DH) + scol;

    for (int kv0 = 0; kv0 < S_LEN; kv0 += 32) {
        // stage K (row-major) and V (transposed)
        *(uint4*)&Ks[srow][scol]      = *(const uint4*)(Kp);
        *(uint4*)&Ks[srow + 16][scol] = *(const uint4*)(Kp + 16 * (NH * DH));
        bf16x8 v0 = *(const bf16x8*)(Vp);
        bf16x8 v1 = *(const bf16x8*)(Vp + 16 * (NH * DH));
        for (int i = 0; i < 8; i++) {
            const int ii = (i + (t & 15)) & 7;  // stagger: 16-way -> 2-way banks
            Vt[scol + ii][srow]      = v0[ii];
            Vt[scol + ii][srow + 16] = v1[ii];
        }
        Kp += (size_t)32 * (NH * DH);
        Vp += (size_t)32 * (NH * DH);
        __syncthreads();

        // S = Q K^T : two 16x16 tiles (kv 0-15 and 16-31)
        floatx4 s0 = {}, s1 = {};
        for (int c = 0; c < 4; c++) {
            bf16x8 kf0 = *(const bf16x8*)&Ks[fr][c * 32 + fq * 8];
            bf16x8 kf1 = *(const bf16x8*)&Ks[fr + 16][c * 32 + fq * 8];
            s0 = __builtin_amdgcn_mfma_f32_16x16x32_bf16(qf[c], kf0, s0, 0, 0, 0);
            s1 = __builtin_amdgcn_mfma_f32_16x16x32_bf16(qf[c], kf1, s1, 0, 0, 0);
        }

        // online softmax per row (row = fq*4 + r; stats reduce over 16 lanes)
        for (int r = 0; r < 4; r++) {
            const float a = s0[r], bb = s1[r];
            float mt = fmaxf(a, bb);
            mt = fmaxf(mt, __shfl_xor(mt, 1, 64));
            mt = fmaxf(mt, __shfl_xor(mt, 2, 64));
            mt = fmaxf(mt, __shfl_xor(mt, 4, 64));
            mt = fmaxf(mt, __shfl_xor(mt, 8, 64));
            const float mnew = fmaxf(m_i[r], mt);
            const float alpha = __expf(sc * (m_i[r] - mnew));
            const __bf16 pb0 = (__bf16)__expf(sc * (a - mnew));
            const __bf16 pb1 = (__bf16)__expf(sc * (bb - mnew));
            Ps[wave][fq * 4 + r][fr]      = pb0;
            Ps[wave][fq * 4 + r][fr + 16] = pb1;
            float ps = (float)pb0 + (float)pb1;  // sum of the values actually fed to PV
            ps += __shfl_xor(ps, 1, 64);
            ps += __shfl_xor(ps, 2, 64);
            ps += __shfl_xor(ps, 4, 64);
            ps += __shfl_xor(ps, 8, 64);
            l_i[r] = l_i[r] * alpha + ps;
            m_i[r] = mnew;
            for (int nb = 0; nb < 8; nb++) oa[nb][r] *= alpha;
        }
        __syncthreads();  // P visible (and K-tile MFMA reads complete)

        // O += P V : A-frag of P from LDS, B-frag of V from transposed tile
        bf16x8 pf = *(const bf16x8*)&Ps[wave][fr][fq * 8];
        for (int nb = 0; nb < 8; nb++) {
            bf16x8 vf = *(const bf16x8*)&Vt[nb * 16 + fr][fq * 8];
            oa[nb] = __builtin_amdgcn_mfma_f32_16x16x32_bf16(pf, vf, oa[nb], 0, 0, 0);
        }
        __syncthreads();  // all tile reads done before next staging
    }

    for (int r = 0; r < 4; r++) {
        const float inv = 1.0f / l_i[r];
        __bf16* op = O + base + (size_t)(q0 + fq * 4 + r) * (NH * DH);
        for (int nb = 0; nb < 8; nb++)
            op[nb * 16 + fr] = (__bf16)(oa[nb][r] * inv);
    }
}

// ---------------------------------------------------------------------------
extern "C" void kernel_launch(void* const* d_in, const int* in_sizes, int n_in,
                              void* d_out, int out_size, void* d_ws, size_t ws_size,
                              hipStream_t stream) {
    const float* x    = (const float*)d_in[0];   // (B,S,DM) fp32
    const float* rope = (const float*)d_in[1];   // (S,1,64,2,2) fp32
    const float* wq   = (const float*)d_in[2];
    const float* wk   = (const float*)d_in[3];
    const float* wv   = (const float*)d_in[4];
    const float* wo   = (const float*)d_in[5];
    const float* qnw  = (const float*)d_in[6];
    const float* knw  = (const float*)d_in[7];
    float* out = (float*)d_out;                  // (B,S,DM) fp32

    const size_t NTOK = 2 * 2048;                // B*S
    const size_t ELEMS = NTOK * 2048;            // 8388608 per bf16 buffer
    __bf16* qb = (__bf16*)d_ws;
    __bf16* kb = qb + ELEMS;
    __bf16* vb = kb + ELEMS;
    __bf16* ob = vb + ELEMS;

    dim3 gg(2048 / 128, (unsigned)(NTOK / 128));  // (16, 32)

    gemm_bt<1, 1, 0><<<gg, 256, 0, stream>>>(x, wq, qb);
    gemm_bt<1, 1, 0><<<gg, 256, 0, stream>>>(x, wk, kb);
    gemm_bt<1, 1, 0><<<gg, 256, 0, stream>>>(x, wv, vb);
    rmsrope<<<dim3(NTOK * 16 / 4, 2), 256, 0, stream>>>(qb, kb, rope, qnw, knw);
    flash<<<dim3(2048 / 64, 2 * 16), 256, 0, stream>>>(qb, kb, vb, ob);
    gemm_bt<0, 1, 1><<<gg, 256, 0, stream>>>(ob, wo, out);
}

// Round 3
// 598.425 us; speedup vs baseline: 1.2629x; 1.2629x over previous
//
#include <hip/hip_runtime.h>

typedef __bf16 bf16x8 __attribute__((ext_vector_type(8)));
typedef __bf16 bf16x4 __attribute__((ext_vector_type(4)));
typedef float floatx4 __attribute__((ext_vector_type(4)));

#define GK 2048
#define GN 2048
#define S_LEN 2048
#define NH 16
#define DH 128

__device__ __forceinline__ void gl2lds16(const __bf16* g, __bf16* l) {
    __builtin_amdgcn_global_load_lds(
        (const __attribute__((address_space(1))) void*)g,
        (__attribute__((address_space(3))) void*)l, 16, 0, 0);
}

// ---------------------------------------------------------------------------
// fp32 -> bf16 bulk convert (grid-stride over float4)
// ---------------------------------------------------------------------------
__global__ __launch_bounds__(256) void cvt_bf16(const float* __restrict__ in,
                                                __bf16* __restrict__ out, int n4) {
    int i = blockIdx.x * 256 + threadIdx.x;
    if (i < n4) {
        const float4 v = ((const float4*)in)[i];
        bf16x4 h;
        h[0] = (__bf16)v.x; h[1] = (__bf16)v.y; h[2] = (__bf16)v.z; h[3] = (__bf16)v.w;
        ((bf16x4*)out)[i] = h;
    }
}

// ---------------------------------------------------------------------------
// GEMM: C[m][n] = sum_k A[m][k] * B[n][k].  A bf16 (global_load_lds staging),
// B fp32 (vector load + cvt). CF32: fp32 C. CT: write C^T as [b][col][s]
// (row = b*2048+s) for the V path.
// 128x128 tile, BK=32, 4 waves, wave = 64x64 (4x4 MFMA 16x16x32 tiles).
// ---------------------------------------------------------------------------
template <int CF32, int CT>
__global__ __launch_bounds__(256) void gemm_abf16(const __bf16* __restrict__ A,
                                                  const float* __restrict__ B,
                                                  void* __restrict__ Cv) {
    __shared__ __align__(16) __bf16 As[128][32];  // unpadded: lane-contiguous for global_load_lds
    __shared__ __align__(16) __bf16 Bs[128][32];

    const int t = threadIdx.x, lane = t & 63, wave = t >> 6;
    const int m0 = blockIdx.y * 128, n0 = blockIdx.x * 128;
    const int wr = (wave >> 1) * 64, wc = (wave & 1) * 64;
    const int fr = lane & 15, fq = lane >> 4;

    floatx4 acc[4][4] = {};

    // A staging: wave w covers rows [w*32, w*32+32); lane -> row w*32+(lane>>2), chunk lane&3
    const __bf16* Ap = A + (size_t)(m0 + wave * 32 + (lane >> 2)) * GK + (lane & 3) * 8;
    __bf16* lA0 = &As[wave * 32][0];       // wave-uniform LDS base, lane*16 implicit
    __bf16* lA1 = &As[wave * 32 + 16][0];

    // B staging: pass p covers rows [p*32, p*32+32); 8 lanes/row, float4 each
    const int br = t >> 3, bc = (t & 7) * 4;
    const float* Bp = B + (size_t)(n0 + br) * GK + bc;

    for (int k0 = 0; k0 < GK; k0 += 32) {
        gl2lds16(Ap, lA0);
        gl2lds16(Ap + (size_t)16 * GK, lA1);
        for (int p = 0; p < 4; p++) {
            const float4 v = *(const float4*)(Bp + (size_t)p * 32 * GK);
            bf16x4 hv;
            hv[0] = (__bf16)v.x; hv[1] = (__bf16)v.y; hv[2] = (__bf16)v.z; hv[3] = (__bf16)v.w;
            *(bf16x4*)&Bs[br + p * 32][bc] = hv;
        }
        Ap += 32; Bp += 32;
        __syncthreads();   // drains vmcnt (global_load_lds) + lds writes

        bf16x8 af[4], bfg[4];
        for (int i = 0; i < 4; i++) af[i]  = *(const bf16x8*)&As[wr + i * 16 + fr][fq * 8];
        for (int j = 0; j < 4; j++) bfg[j] = *(const bf16x8*)&Bs[wc + j * 16 + fr][fq * 8];
        for (int i = 0; i < 4; i++)
            for (int j = 0; j < 4; j++)
                acc[i][j] = __builtin_amdgcn_mfma_f32_16x16x32_bf16(af[i], bfg[j], acc[i][j], 0, 0, 0);
        __syncthreads();
    }

    // C/D layout: row = fq*4 + r, col = fr  [m89-verified]
    for (int i = 0; i < 4; i++)
        for (int j = 0; j < 4; j++) {
            const int row = m0 + wr + i * 16 + fq * 4;
            const int col = n0 + wc + j * 16 + fr;
            if (CT) {
                // vbT[b][col][s]: idx = (row & ~2047)*2048 + col*2048 + (row & 2047)
                __bf16* Cp = (__bf16*)Cv + (((size_t)(row & ~2047)) << 11) +
                             (size_t)col * 2048 + (row & 2047);
                bf16x4 hv;
                for (int r = 0; r < 4; r++) hv[r] = (__bf16)acc[i][j][r];
                *(bf16x4*)Cp = hv;    // 4 consecutive s, 8B aligned (row%4==0)
            } else if (CF32) {
                for (int r = 0; r < 4; r++)
                    ((float*)Cv)[(size_t)(row + r) * GN + col] = acc[i][j][r];
            } else {
                for (int r = 0; r < 4; r++)
                    ((__bf16*)Cv)[(size_t)(row + r) * GN + col] = (__bf16)acc[i][j][r];
            }
        }
}

// ---------------------------------------------------------------------------
// Fused RMSNorm (per head, DH=128, fp32 math) + RoPE, in-place on bf16 q/k.
// One wave per (b,s,h) row: lane j holds elems j and j+64 (the RoPE pair).
// ---------------------------------------------------------------------------
__global__ __launch_bounds__(256) void rmsrope(__bf16* __restrict__ qb,
                                               __bf16* __restrict__ kb,
                                               const float* __restrict__ rope,
                                               const float* __restrict__ qw,
                                               const float* __restrict__ kw) {
    const int lane = threadIdx.x & 63;
    const int row = blockIdx.x * 4 + (threadIdx.x >> 6);   // (b*S + s)*H + h
    __bf16* p = (blockIdx.y ? kb : qb) + (size_t)row * DH;
    const float* w = blockIdx.y ? kw : qw;
    const int s = (row >> 4) & (S_LEN - 1);

    float t0 = (float)p[lane];
    float t1 = (float)p[lane + 64];
    float ss = t0 * t0 + t1 * t1;
    for (int o = 32; o; o >>= 1) ss += __shfl_xor(ss, o, 64);
    const float inv = rsqrtf(ss * (1.0f / 128.0f) + 1e-6f);
    t0 *= inv * w[lane];
    t1 *= inv * w[lane + 64];

    const float4 f = *(const float4*)(rope + (size_t)s * 256 + lane * 4);  // (S,1,64,2,2)
    p[lane]      = (__bf16)(f.x * t0 + f.y * t1);
    p[lane + 64] = (__bf16)(f.z * t0 + f.w * t1);
}

// ---------------------------------------------------------------------------
// Flash attention v2: fixed-max softmax (scores bounded: q,k unit-RMS, rope
// blocks ~N(0,1) -> |s| << 80; p = exp(s*sc - 12), scale cancels in O/l).
// l accumulated via MFMA ones-column (Vt row 128 = 1, rows 129-143 = 0).
// grid = (S/128, B*H), 4 waves x 32 q-rows. KV tile 32. V^T pre-transposed
// in HBM (vbT[b][h][d][s]) so all staging is vectorized.
// ---------------------------------------------------------------------------
__global__ __launch_bounds__(256) void flash(const __bf16* __restrict__ Q,
                                             const __bf16* __restrict__ K,
                                             const __bf16* __restrict__ Vt_g,
                                             __bf16* __restrict__ O) {
    __shared__ __align__(16) __bf16 Ks[32][136];    // [kv][d], pad 8
    __shared__ __align__(16) __bf16 Vt[144][40];    // [d][kv], rows 128+ = ones/zeros
    __shared__ __align__(16) __bf16 Ps[4][32][40];  // per-wave P [qr][kv]

    const int t = threadIdx.x, lane = t & 63, wave = t >> 6;
    const int fr = lane & 15, fq = lane >> 4;
    const int b = blockIdx.y >> 4, h = blockIdx.y & 15;
    const size_t baseQ = (size_t)b * S_LEN * 2048 + h * 128;          // q/k/o: [b][s][h*128+d]
    const size_t baseV = (size_t)b * 2048 * 2048 + (size_t)h * 128 * 2048;  // vbT: [b][h*128+d][s]
    const int q0 = blockIdx.x * 128 + wave * 32;
    const float sc = 0.08838834764831845f;  // 1/sqrt(128)
    const float M = 12.0f;

    // ones/zero rows for the l-column (written once; first in-loop barrier orders it)
    for (int idx = t; idx < 16 * 40; idx += 256) {
        const int rr = idx / 40, cc = idx - rr * 40;
        Vt[128 + rr][cc] = (rr == 0) ? (__bf16)1.0f : (__bf16)0.0f;
    }

    // Q fragments (A layout): 2 row-subtiles x 4 k-chunks
    bf16x8 qf[2][4];
    for (int i2 = 0; i2 < 2; i2++) {
        const __bf16* qp = Q + baseQ + (size_t)(q0 + i2 * 16 + fr) * 2048 + fq * 8;
        for (int c = 0; c < 4; c++) qf[i2][c] = *(const bf16x8*)(qp + c * 32);
    }

    floatx4 oa[2][9] = {};   // [row-subtile][8 d-tiles + l-tile]

    const __bf16* Kp = K + baseQ + (size_t)(t >> 3) * 2048 + (t & 7) * 16;
    const __bf16* Vp = Vt_g + baseV + (size_t)(t >> 1) * 2048 + (t & 1) * 16;

    for (int kv0 = 0; kv0 < S_LEN; kv0 += 32) {
        *(uint4*)&Ks[t >> 3][(t & 7) * 16]     = *(const uint4*)(Kp);
        *(uint4*)&Ks[t >> 3][(t & 7) * 16 + 8] = *(const uint4*)(Kp + 8);
        *(uint4*)&Vt[t >> 1][(t & 1) * 16]     = *(const uint4*)(Vp);
        *(uint4*)&Vt[t >> 1][(t & 1) * 16 + 8] = *(const uint4*)(Vp + 8);
        Kp += (size_t)32 * 2048;
        Vp += 32;
        __syncthreads();

        // S = Q K^T: 2 row-subtiles x 2 kv-subtiles
        floatx4 sacc[2][2] = {};
        for (int c = 0; c < 4; c++) {
            const bf16x8 kf0 = *(const bf16x8*)&Ks[fr][c * 32 + fq * 8];
            const bf16x8 kf1 = *(const bf16x8*)&Ks[fr + 16][c * 32 + fq * 8];
            sacc[0][0] = __builtin_amdgcn_mfma_f32_16x16x32_bf16(qf[0][c], kf0, sacc[0][0], 0, 0, 0);
            sacc[0][1] = __builtin_amdgcn_mfma_f32_16x16x32_bf16(qf[0][c], kf1, sacc[0][1], 0, 0, 0);
            sacc[1][0] = __builtin_amdgcn_mfma_f32_16x16x32_bf16(qf[1][c], kf0, sacc[1][0], 0, 0, 0);
            sacc[1][1] = __builtin_amdgcn_mfma_f32_16x16x32_bf16(qf[1][c], kf1, sacc[1][1], 0, 0, 0);
        }

        // P = exp(s*sc - M), straight to LDS (C-layout row = fq*4+r, col = fr)
        for (int i2 = 0; i2 < 2; i2++)
            for (int r = 0; r < 4; r++) {
                const int row = i2 * 16 + fq * 4 + r;
                Ps[wave][row][fr]      = (__bf16)__expf(fmaf(sc, sacc[i2][0][r], -M));
                Ps[wave][row][fr + 16] = (__bf16)__expf(fmaf(sc, sacc[i2][1][r], -M));
            }

        // O += P V (and l += P 1 in tile 8); per-wave Ps: no barrier needed
        const bf16x8 pf0 = *(const bf16x8*)&Ps[wave][fr][fq * 8];
        const bf16x8 pf1 = *(const bf16x8*)&Ps[wave][16 + fr][fq * 8];
        for (int nb = 0; nb < 9; nb++) {
            const bf16x8 vf = *(const bf16x8*)&Vt[nb * 16 + fr][fq * 8];
            oa[0][nb] = __builtin_amdgcn_mfma_f32_16x16x32_bf16(pf0, vf, oa[0][nb], 0, 0, 0);
            oa[1][nb] = __builtin_amdgcn_mfma_f32_16x16x32_bf16(pf1, vf, oa[1][nb], 0, 0, 0);
        }
        __syncthreads();   // tile reads done before next staging
    }

    for (int i2 = 0; i2 < 2; i2++)
        for (int r = 0; r < 4; r++) {
            float l = oa[i2][8][r];          // col 128 lives at fr==0
            l = __shfl(l, fq * 16);          // broadcast within the fq row-group
            const float inv = 1.0f / l;
            __bf16* op = O + baseQ + (size_t)(q0 + i2 * 16 + fq * 4 + r) * 2048;
            for (int nb = 0; nb < 8; nb++)
                op[nb * 16 + fr] = (__bf16)(oa[i2][nb][r] * inv);
        }
}

// ---------------------------------------------------------------------------
extern "C" void kernel_launch(void* const* d_in, const int* in_sizes, int n_in,
                              void* d_out, int out_size, void* d_ws, size_t ws_size,
                              hipStream_t stream) {
    const float* x    = (const float*)d_in[0];
    const float* rope = (const float*)d_in[1];
    const float* wq   = (const float*)d_in[2];
    const float* wk   = (const float*)d_in[3];
    const float* wv   = (const float*)d_in[4];
    const float* wo   = (const float*)d_in[5];
    const float* qnw  = (const float*)d_in[6];
    const float* knw  = (const float*)d_in[7];
    float* out = (float*)d_out;

    const size_t NTOK = 2 * 2048;
    const size_t ELEMS = NTOK * 2048;            // 8388608
    __bf16* xb  = (__bf16*)d_ws;                 // phase 1; aliased by ob later
    __bf16* qb  = xb + ELEMS;
    __bf16* kb  = qb + ELEMS;
    __bf16* vbT = kb + ELEMS;
    __bf16* ob  = xb;                            // flash output reuses xb region

    dim3 gg(GN / 128, (unsigned)(NTOK / 128));   // (16, 32)

    cvt_bf16<<<(int)(ELEMS / 4 + 255) / 256, 256, 0, stream>>>(x, xb, (int)(ELEMS / 4));
    gemm_abf16<0, 0><<<gg, 256, 0, stream>>>(xb, wq, qb);
    gemm_abf16<0, 0><<<gg, 256, 0, stream>>>(xb, wk, kb);
    gemm_abf16<0, 1><<<gg, 256, 0, stream>>>(xb, wv, vbT);
    rmsrope<<<dim3((unsigned)(NTOK * 16 / 4), 2), 256, 0, stream>>>(qb, kb, rope, qnw, knw);
    flash<<<dim3(S_LEN / 128, 2 * 16), 256, 0, stream>>>(qb, kb, vbT, ob);
    gemm_abf16<1, 0><<<gg, 256, 0, stream>>>(ob, wo, out);
}

// Round 4
// 452.501 us; speedup vs baseline: 1.6701x; 1.3225x over previous
//
#include <hip/hip_runtime.h>

typedef __bf16 bf16x8 __attribute__((ext_vector_type(8)));
typedef __bf16 bf16x4 __attribute__((ext_vector_type(4)));
typedef float floatx4 __attribute__((ext_vector_type(4)));

#define GK 2048
#define S_LEN 2048
#define NH 16
#define DH 128

__device__ __forceinline__ void gl2lds16(const __bf16* g, __bf16* l) {
    __builtin_amdgcn_global_load_lds(
        (const __attribute__((address_space(1))) void*)g,
        (__attribute__((address_space(3))) void*)l, 16, 0, 0);
}

// ---------------------------------------------------------------------------
// fp32 -> bf16 bulk convert (one float4 -> bf16x4 per thread)
// ---------------------------------------------------------------------------
__global__ __launch_bounds__(256) void cvt_bf16(const float* __restrict__ in,
                                                __bf16* __restrict__ out, int n4) {
    int i = blockIdx.x * 256 + threadIdx.x;
    if (i < n4) {
        const float4 v = ((const float4*)in)[i];
        bf16x4 h;
        h[0] = (__bf16)v.x; h[1] = (__bf16)v.y; h[2] = (__bf16)v.z; h[3] = (__bf16)v.w;
        ((bf16x4*)out)[i] = h;
    }
}

// concat-convert wq|wk|wv (each 2048x2048 fp32) -> one bf16 [6144][2048]
__global__ __launch_bounds__(256) void cvt3_bf16(const float* __restrict__ a,
                                                 const float* __restrict__ b,
                                                 const float* __restrict__ c,
                                                 __bf16* __restrict__ out) {
    const int per = 2048 * 2048 / 4;
    int i = blockIdx.x * 256 + threadIdx.x;      // 0 .. 3*per-1
    const float* src = a; int j = i;
    if (i >= 2 * per)      { src = c; j = i - 2 * per; }
    else if (i >= per)     { src = b; j = i - per; }
    const float4 v = ((const float4*)src)[j];
    bf16x4 h;
    h[0] = (__bf16)v.x; h[1] = (__bf16)v.y; h[2] = (__bf16)v.z; h[3] = (__bf16)v.w;
    ((bf16x4*)out)[i] = h;
}

// ---------------------------------------------------------------------------
// Pure-bf16 K-loop: C[m][n] = sum_k A[m][k] * W[n][k], both staged via
// global_load_lds width-16. 128x128 tile, BK=32, 4 waves, 4x4 MFMA/wave.
// ---------------------------------------------------------------------------
__device__ __forceinline__ void gemm_body(const __bf16* __restrict__ A,
                                          const __bf16* __restrict__ W,
                                          int m0, int n0,
                                          __bf16 (*As)[32], __bf16 (*Bs)[32],
                                          floatx4 (*acc)[4]) {
    const int t = threadIdx.x, lane = t & 63, wave = t >> 6;
    const int fr = lane & 15, fq = lane >> 4;
    const int wr = (wave >> 1) * 64, wc = (wave & 1) * 64;

    const __bf16* Ap = A + (size_t)(m0 + wave * 32 + (lane >> 2)) * GK + (lane & 3) * 8;
    const __bf16* Wp = W + (size_t)(n0 + wave * 32 + (lane >> 2)) * GK + (lane & 3) * 8;
    __bf16* lA0 = &As[wave * 32][0];
    __bf16* lA1 = &As[wave * 32 + 16][0];
    __bf16* lB0 = &Bs[wave * 32][0];
    __bf16* lB1 = &Bs[wave * 32 + 16][0];

    for (int k0 = 0; k0 < GK; k0 += 32) {
        gl2lds16(Ap, lA0);
        gl2lds16(Ap + (size_t)16 * GK, lA1);
        gl2lds16(Wp, lB0);
        gl2lds16(Wp + (size_t)16 * GK, lB1);
        Ap += 32; Wp += 32;
        __syncthreads();   // drains vmcnt + orders LDS

        bf16x8 af[4], bfg[4];
        for (int i = 0; i < 4; i++) af[i]  = *(const bf16x8*)&As[wr + i * 16 + fr][fq * 8];
        for (int j = 0; j < 4; j++) bfg[j] = *(const bf16x8*)&Bs[wc + j * 16 + fr][fq * 8];
        for (int i = 0; i < 4; i++)
            for (int j = 0; j < 4; j++)
                acc[i][j] = __builtin_amdgcn_mfma_f32_16x16x32_bf16(af[i], bfg[j], acc[i][j], 0, 0, 0);
        __syncthreads();
    }
}

// Fused QKV projection: A (4096x2048 bf16) x Wqkv (6144x2048 bf16).
// n<2048 -> qb, n<4096 -> kb (row-major [b*S][2048]); n>=4096 -> vbT
// ([b][h*128+d][s], transposed for flash staging).
__global__ __launch_bounds__(256) void gemm_qkv(const __bf16* __restrict__ A,
                                                const __bf16* __restrict__ W,
                                                __bf16* __restrict__ qb,
                                                __bf16* __restrict__ kb,
                                                __bf16* __restrict__ vbT) {
    __shared__ __align__(16) __bf16 As[128][32];
    __shared__ __align__(16) __bf16 Bs[128][32];
    const int m0 = blockIdx.y * 128, n0 = blockIdx.x * 128;
    floatx4 acc[4][4] = {};
    gemm_body(A, W, m0, n0, As, Bs, acc);

    const int lane = threadIdx.x & 63, wave = threadIdx.x >> 6;
    const int fr = lane & 15, fq = lane >> 4;
    const int wr = (wave >> 1) * 64, wc = (wave & 1) * 64;
    const int which = n0 >> 11;          // 0=q 1=k 2=v (block-uniform)
    const int nc0 = n0 & 2047;

    for (int i = 0; i < 4; i++)
        for (int j = 0; j < 4; j++) {
            const int row = m0 + wr + i * 16 + fq * 4;
            const int col = nc0 + wc + j * 16 + fr;
            if (which == 2) {
                // vbT[b][col][s]; b = row>>11, s = row&2047 (row%4==0 -> 8B aligned)
                __bf16* Cp = vbT + (((size_t)(row & ~2047)) << 11) +
                             (size_t)col * 2048 + (row & 2047);
                bf16x4 hv;
                for (int r = 0; r < 4; r++) hv[r] = (__bf16)acc[i][j][r];
                *(bf16x4*)Cp = hv;
            } else {
                __bf16* dst = which ? kb : qb;
                for (int r = 0; r < 4; r++)
                    dst[(size_t)(row + r) * 2048 + col] = (__bf16)acc[i][j][r];
            }
        }
}

// Out-projection: A (4096x2048 bf16) x Wo (2048x2048 bf16) -> fp32 out
__global__ __launch_bounds__(256) void gemm_out(const __bf16* __restrict__ A,
                                                const __bf16* __restrict__ W,
                                                float* __restrict__ C) {
    __shared__ __align__(16) __bf16 As[128][32];
    __shared__ __align__(16) __bf16 Bs[128][32];
    const int m0 = blockIdx.y * 128, n0 = blockIdx.x * 128;
    floatx4 acc[4][4] = {};
    gemm_body(A, W, m0, n0, As, Bs, acc);

    const int lane = threadIdx.x & 63, wave = threadIdx.x >> 6;
    const int fr = lane & 15, fq = lane >> 4;
    const int wr = (wave >> 1) * 64, wc = (wave & 1) * 64;
    for (int i = 0; i < 4; i++)
        for (int j = 0; j < 4; j++) {
            const int row = m0 + wr + i * 16 + fq * 4;
            const int col = n0 + wc + j * 16 + fr;
            for (int r = 0; r < 4; r++)
                C[(size_t)(row + r) * 2048 + col] = acc[i][j][r];
        }
}

// ---------------------------------------------------------------------------
// Fused RMSNorm (per head, DH=128, fp32 math) + RoPE, in-place on bf16 q/k.
// ---------------------------------------------------------------------------
__global__ __launch_bounds__(256) void rmsrope(__bf16* __restrict__ qb,
                                               __bf16* __restrict__ kb,
                                               const float* __restrict__ rope,
                                               const float* __restrict__ qw,
                                               const float* __restrict__ kw) {
    const int lane = threadIdx.x & 63;
    const int row = blockIdx.x * 4 + (threadIdx.x >> 6);   // (b*S + s)*H + h
    __bf16* p = (blockIdx.y ? kb : qb) + (size_t)row * DH;
    const float* w = blockIdx.y ? kw : qw;
    const int s = (row >> 4) & (S_LEN - 1);

    float t0 = (float)p[lane];
    float t1 = (float)p[lane + 64];
    float ss = t0 * t0 + t1 * t1;
    for (int o = 32; o; o >>= 1) ss += __shfl_xor(ss, o, 64);
    const float inv = rsqrtf(ss * (1.0f / 128.0f) + 1e-6f);
    t0 *= inv * w[lane];
    t1 *= inv * w[lane + 64];

    const float4 f = *(const float4*)(rope + (size_t)s * 256 + lane * 4);
    p[lane]      = (__bf16)(f.x * t0 + f.y * t1);
    p[lane + 64] = (__bf16)(f.z * t0 + f.w * t1);
}

// ---------------------------------------------------------------------------
// Flash attention: fixed-max softmax (p = exp2(s*sc*log2e - M2)), l via MFMA
// ones-column. grid = (S/128, B*H), 4 waves x 32 q-rows, KV tile 32.
// ---------------------------------------------------------------------------
__global__ __launch_bounds__(256) void flash(const __bf16* __restrict__ Q,
                                             const __bf16* __restrict__ K,
                                             const __bf16* __restrict__ Vt_g,
                                             __bf16* __restrict__ O) {
    __shared__ __align__(16) __bf16 Ks[32][136];
    __shared__ __align__(16) __bf16 Vt[144][40];
    __shared__ __align__(16) __bf16 Ps[4][32][40];

    const int t = threadIdx.x, lane = t & 63, wave = t >> 6;
    const int fr = lane & 15, fq = lane >> 4;
    const int b = blockIdx.y >> 4, h = blockIdx.y & 15;
    const size_t baseQ = (size_t)b * S_LEN * 2048 + h * 128;
    const size_t baseV = (size_t)b * 2048 * 2048 + (size_t)h * 128 * 2048;
    const int q0 = blockIdx.x * 128 + wave * 32;
    const float sc2 = 0.08838834764831845f * 1.4426950408889634f;  // (1/sqrt(128))*log2e
    const float M2 = 12.0f * 1.4426950408889634f;

    for (int idx = t; idx < 16 * 40; idx += 256) {
        const int rr = idx / 40, cc = idx - rr * 40;
        Vt[128 + rr][cc] = (rr == 0) ? (__bf16)1.0f : (__bf16)0.0f;
    }

    bf16x8 qf[2][4];
    for (int i2 = 0; i2 < 2; i2++) {
        const __bf16* qp = Q + baseQ + (size_t)(q0 + i2 * 16 + fr) * 2048 + fq * 8;
        for (int c = 0; c < 4; c++) qf[i2][c] = *(const bf16x8*)(qp + c * 32);
    }

    floatx4 oa[2][9] = {};

    const __bf16* Kp = K + baseQ + (size_t)(t >> 3) * 2048 + (t & 7) * 16;
    const __bf16* Vp = Vt_g + baseV + (size_t)(t >> 1) * 2048 + (t & 1) * 16;

    for (int kv0 = 0; kv0 < S_LEN; kv0 += 32) {
        *(uint4*)&Ks[t >> 3][(t & 7) * 16]     = *(const uint4*)(Kp);
        *(uint4*)&Ks[t >> 3][(t & 7) * 16 + 8] = *(const uint4*)(Kp + 8);
        *(uint4*)&Vt[t >> 1][(t & 1) * 16]     = *(const uint4*)(Vp);
        *(uint4*)&Vt[t >> 1][(t & 1) * 16 + 8] = *(const uint4*)(Vp + 8);
        Kp += (size_t)32 * 2048;
        Vp += 32;
        __syncthreads();

        floatx4 sacc[2][2] = {};
        for (int c = 0; c < 4; c++) {
            const bf16x8 kf0 = *(const bf16x8*)&Ks[fr][c * 32 + fq * 8];
            const bf16x8 kf1 = *(const bf16x8*)&Ks[fr + 16][c * 32 + fq * 8];
            sacc[0][0] = __builtin_amdgcn_mfma_f32_16x16x32_bf16(qf[0][c], kf0, sacc[0][0], 0, 0, 0);
            sacc[0][1] = __builtin_amdgcn_mfma_f32_16x16x32_bf16(qf[0][c], kf1, sacc[0][1], 0, 0, 0);
            sacc[1][0] = __builtin_amdgcn_mfma_f32_16x16x32_bf16(qf[1][c], kf0, sacc[1][0], 0, 0, 0);
            sacc[1][1] = __builtin_amdgcn_mfma_f32_16x16x32_bf16(qf[1][c], kf1, sacc[1][1], 0, 0, 0);
        }

        for (int i2 = 0; i2 < 2; i2++)
            for (int r = 0; r < 4; r++) {
                const int row = i2 * 16 + fq * 4 + r;
                Ps[wave][row][fr]      = (__bf16)exp2f(fmaf(sc2, sacc[i2][0][r], -M2));
                Ps[wave][row][fr + 16] = (__bf16)exp2f(fmaf(sc2, sacc[i2][1][r], -M2));
            }

        const bf16x8 pf0 = *(const bf16x8*)&Ps[wave][fr][fq * 8];
        const bf16x8 pf1 = *(const bf16x8*)&Ps[wave][16 + fr][fq * 8];
        for (int nb = 0; nb < 9; nb++) {
            const bf16x8 vf = *(const bf16x8*)&Vt[nb * 16 + fr][fq * 8];
            oa[0][nb] = __builtin_amdgcn_mfma_f32_16x16x32_bf16(pf0, vf, oa[0][nb], 0, 0, 0);
            oa[1][nb] = __builtin_amdgcn_mfma_f32_16x16x32_bf16(pf1, vf, oa[1][nb], 0, 0, 0);
        }
        __syncthreads();
    }

    for (int i2 = 0; i2 < 2; i2++)
        for (int r = 0; r < 4; r++) {
            float l = oa[i2][8][r];
            l = __shfl(l, fq * 16);
            const float inv = 1.0f / l;
            __bf16* op = O + baseQ + (size_t)(q0 + i2 * 16 + fq * 4 + r) * 2048;
            for (int nb = 0; nb < 8; nb++)
                op[nb * 16 + fr] = (__bf16)(oa[i2][nb][r] * inv);
        }
}

// ---------------------------------------------------------------------------
extern "C" void kernel_launch(void* const* d_in, const int* in_sizes, int n_in,
                              void* d_out, int out_size, void* d_ws, size_t ws_size,
                              hipStream_t stream) {
    const float* x    = (const float*)d_in[0];
    const float* rope = (const float*)d_in[1];
    const float* wq   = (const float*)d_in[2];
    const float* wk   = (const float*)d_in[3];
    const float* wv   = (const float*)d_in[4];
    const float* wo   = (const float*)d_in[5];
    const float* qnw  = (const float*)d_in[6];
    const float* knw  = (const float*)d_in[7];
    float* out = (float*)d_out;

    const size_t NTOK = 2 * 2048;
    const size_t ELEMS = NTOK * 2048;            // 8388608
    __bf16* xb  = (__bf16*)d_ws;                 // 16 MB; reused as ob after flash
    __bf16* qb  = xb + ELEMS;                    // 16 MB; reused for wo_bf after flash
    __bf16* kb  = qb + ELEMS;
    __bf16* vbT = kb + ELEMS;
    __bf16* ob  = xb;
    // d_out (32 MB fp32) doubles as scratch for the concatenated bf16 QKV
    // weights (25.2 MB) — fully consumed by gemm_qkv before gemm_out writes it.
    __bf16* wqkv = (__bf16*)d_out;
    __bf16* wob  = qb;                           // wo bf16 (8 MB), written after flash

    cvt_bf16<<<(int)(ELEMS / 4) / 256, 256, 0, stream>>>(x, xb, (int)(ELEMS / 4));
    cvt3_bf16<<<3 * (2048 * 2048 / 4) / 256, 256, 0, stream>>>(wq, wk, wv, wqkv);
    gemm_qkv<<<dim3(6144 / 128, (unsigned)(NTOK / 128)), 256, 0, stream>>>(xb, wqkv, qb, kb, vbT);
    rmsrope<<<dim3((unsigned)(NTOK * 16 / 4), 2), 256, 0, stream>>>(qb, kb, rope, qnw, knw);
    flash<<<dim3(S_LEN / 128, 2 * 16), 256, 0, stream>>>(qb, kb, vbT, ob);
    cvt_bf16<<<(int)(2048 * 2048 / 4) / 256, 256, 0, stream>>>(wo, wob, 2048 * 2048 / 4);
    gemm_out<<<dim3(2048 / 128, (unsigned)(NTOK / 128)), 256, 0, stream>>>(ob, wob, out);
}